// Round 3
// baseline (490.800 us; speedup 1.0000x reference)
//
#include <hip/hip_runtime.h>
#include <hip/hip_bf16.h>

// One-hot expansion: mask [1,1,256,256,48] fp32 labels in 0..40 ->
// out [1,40,256,256,48] fp32, out[n,v] = (mask[v] == n+1).
//
// R1: 40 interleaved plane-stride store streams per wave -> 1 TB/s. Fixed
//     with one plane per blockIdx.y, contiguous float4 stores (474 us total,
//     onehot dispatch ~155 us; the ~320 us harness re-poison fill is in the
//     timed graph and is our floor).
// R2/R3: nt stores to keep the mask LLC-resident -> exactly neutral.
//     So either nt doesn't control MALL allocation, or the mask re-reads
//     already hit cache and the ~155 us is a write-side/granularity limit
//     (503 MB / 155 us = 3.2 TB/s, half the fill kernel's write BW, with
//     only 16 B loaded + 16 B stored per thread).
// R4: structural fix covering both: G=8 planes per block. One mask float4
//     load feeds 8 plane stores -> mask traffic /8 (63 MB) AND 9x work per
//     thread (15,360 blocks instead of 122,880). Each store instruction is
//     still 1 KB contiguous per wave; 8 concurrent write streams (vs R1's
//     pathological 40).

constexpr int V = 256 * 256 * 48;   // 3,145,728 voxels per plane
constexpr int N_LABELS = 40;
constexpr int G = 8;                // planes per block (40 = 5 groups of 8)

typedef float f32x4 __attribute__((ext_vector_type(4)));

__global__ __launch_bounds__(256)
void onehot_kernel(const float* __restrict__ mask, float* __restrict__ out) {
    const int i = (blockIdx.x * blockDim.x + threadIdx.x) * 4;  // voxel index
    const int n0 = blockIdx.y * G;                              // first plane

    const f32x4 m = *reinterpret_cast<const f32x4*>(mask + i);

#pragma unroll
    for (int g = 0; g < G; ++g) {
        const float lab = (float)(n0 + g + 1);
        f32x4 o;
        o.x = (m.x == lab) ? 1.0f : 0.0f;
        o.y = (m.y == lab) ? 1.0f : 0.0f;
        o.z = (m.z == lab) ? 1.0f : 0.0f;
        o.w = (m.w == lab) ? 1.0f : 0.0f;
        *reinterpret_cast<f32x4*>(out + (size_t)(n0 + g) * V + i) = o;
    }
}

extern "C" void kernel_launch(void* const* d_in, const int* in_sizes, int n_in,
                              void* d_out, int out_size, void* d_ws, size_t ws_size,
                              hipStream_t stream) {
    const float* mask = (const float*)d_in[0];
    float* out = (float*)d_out;

    const int threads = 256;
    const int blocks_x = (V / 4) / threads;   // 3,072 chunks per plane
    dim3 grid(blocks_x, N_LABELS / G);        // 15,360 blocks total

    onehot_kernel<<<grid, threads, 0, stream>>>(mask, out);
}

// Round 4
// 489.873 us; speedup vs baseline: 1.0019x; 1.0019x over previous
//
#include <hip/hip_runtime.h>
#include <hip/hip_bf16.h>

// One-hot expansion: mask [1,1,256,256,48] fp32 labels in 0..40 ->
// out [1,40,256,256,48] fp32, out[n,v] = (mask[v] == n+1).
//
// R1: 40 per-instruction-interleaved plane-stride store streams -> 1 TB/s.
// R2/R3: nt stores (keep mask LLC-resident) -> exactly neutral.
// R4: G=8 planes/block (1 KB burst per plane per wave, per-instruction
//     interleave) -> 3.4 TB/s effective, slight regression. Read cut was
//     fully offset by write-BW loss. Penalty curve: 40 streams = 1 TB/s,
//     8 streams = 3.4 TB/s, 1 stream = 6.5 TB/s.
// R5: G=1 is roofline-bound for ~1 GB traffic (writes 503 MB + mask
//     re-read 40x = 490 MB at 6.5 TB/s = 155 us). To go faster, cut reads
//     WITHOUT interleaving stores: mask chunk lives in REGISTERS (16
//     voxels/thread), plane loop is sequential with one 16 KB contiguous
//     burst per plane per block. Blocks march planes in near-lockstep ->
//     global write pattern is nearly plane-sequential. Mask traffic: 13 MB.

constexpr int V = 256 * 256 * 48;   // 3,145,728 voxels per plane
constexpr int N_LABELS = 40;
constexpr int TPB = 256;
constexpr int VPT = 16;             // voxels per thread (4x float4, 16 VGPRs)
constexpr int CHUNK = TPB * VPT;    // 4096 voxels = 16 KB per block

typedef float f32x4 __attribute__((ext_vector_type(4)));

__global__ __launch_bounds__(TPB)
void onehot_kernel(const float* __restrict__ mask, float* __restrict__ out) {
    const int base = blockIdx.x * CHUNK;
    const int toff = threadIdx.x * 4;

    // Load this block's 16 KB mask chunk once, wave-contiguous per k.
    f32x4 m[4];
#pragma unroll
    for (int k = 0; k < 4; ++k)
        m[k] = *reinterpret_cast<const f32x4*>(mask + base + k * (TPB * 4) + toff);

    // Sequential plane loop: one contiguous 16 KB store burst per plane.
    for (int n = 0; n < N_LABELS; ++n) {
        const float lab = (float)(n + 1);
        float* op = out + (size_t)n * V + base + toff;
#pragma unroll
        for (int k = 0; k < 4; ++k) {
            f32x4 o;
            o.x = (m[k].x == lab) ? 1.0f : 0.0f;
            o.y = (m[k].y == lab) ? 1.0f : 0.0f;
            o.z = (m[k].z == lab) ? 1.0f : 0.0f;
            o.w = (m[k].w == lab) ? 1.0f : 0.0f;
            *reinterpret_cast<f32x4*>(op + k * (TPB * 4)) = o;
        }
    }
}

extern "C" void kernel_launch(void* const* d_in, const int* in_sizes, int n_in,
                              void* d_out, int out_size, void* d_ws, size_t ws_size,
                              hipStream_t stream) {
    const float* mask = (const float*)d_in[0];
    float* out = (float*)d_out;

    dim3 grid(V / CHUNK);  // 768 blocks, 3 per CU, 12 waves/CU

    onehot_kernel<<<grid, TPB, 0, stream>>>(mask, out);
}